// Round 6
// baseline (60.845 us; speedup 1.0000x reference)
//
#include <hip/hip_runtime.h>

#define A_COUNT 24576
#define B_COUNT 32
#define NOBJ 16
#define C_COUNT 21

#define NCH 64                      // anchor chunks in k_match
#define CHUNK (A_COUNT / NCH)       // 384 anchors per k_match block
#define NB 2048                     // partial count (k_match 64x32 grid; k_focal blocks)
#define TOTAL4 (B_COUNT * A_COUNT * C_COUNT / 4)  // 4128768

#define TBL_N 2048
#define TBL_LO 8.0f                 // table spans [-8, 8]
#define TBL_STEP (16.0f / (float)TBL_N)
#define TBL_SCALE ((float)TBL_N / 16.0f)

// ---- workspace layout (bytes); every slot fully rewritten every call ----
#define WS_BPP 0                              // u64 [512][64] = 256 KB
#define WS_LOCP (512 * 64 * 8)                // f32 [NB]
#define WS_CORR (WS_LOCP + NB * 4)            // f32 [NB]
#define WS_POSP (WS_CORR + NB * 4)            // u32 [NB]
#define WS_CLSP (WS_POSP + NB * 4)            // f32 [NB]

__device__ __forceinline__ unsigned long long pack_key(float iou, int a) {
    unsigned int ib = __float_as_uint(iou);  // iou >= 0 so uint order == float order
    return ((unsigned long long)ib << 32) | (unsigned long long)(0xFFFFFFFFu - (unsigned int)a);
}

__device__ __forceinline__ float iou_pf(float tx0, float ty0, float tx1, float ty1, float at,
                                        float x0, float y0, float x1, float y1, float ap) {
    float lx = fmaxf(tx0, x0), ly = fmaxf(ty0, y0);
    float rx = fminf(tx1, x1), ry = fminf(ty1, y1);
    float w = fmaxf(rx - lx, 0.0f), h = fmaxf(ry - ly, 0.0f);
    float inter = w * h;
    return inter / (at + ap - inter);
}

__device__ __forceinline__ float sl1(float d) {
    float ad = fabsf(d);
    return (ad < 1.0f) ? 0.5f * d * d : ad - 0.5f;
}

// smooth-L1 for one positive anchor (t point-form, an center-form, lp prediction)
__device__ __forceinline__ float loc_term(float4 t, float4 an, float4 lp) {
    float gx = ((t.x + t.z) * 0.5f - an.x) / (0.1f * an.z);
    float gy = ((t.y + t.w) * 0.5f - an.y) / (0.1f * an.w);
    float gw = __logf((t.z - t.x) / an.z) * 5.0f;
    float gh = __logf((t.w - t.y) / an.w) * 5.0f;
    return sl1(lp.x - gx) + sl1(lp.y - gy) + sl1(lp.z - gw) + sl1(lp.w - gh);
}

// exact focal correction at the matched class column:
// + 0.25*(1-p)^2*(-ln p)  and  - 0.75*p^2*ln(1+e^x)  (removes the t=0 main term)
__device__ __forceinline__ float corr_term(float x) {
    float E = __expf(x);
    float den = 1.0f + E;
    float s = __builtin_amdgcn_rcpf(den);   // 1-p
    float p = E * s;
    float L = __logf(den);                  // ln(1+e^x); -ln p = L - x
    return 0.25f * s * s * (L - x) - 0.75f * p * p * L;
}

// Kernel 1: focal main term for ALL non-background logits via LDS
// piecewise-linear table (no transcendentals in hot loop), coalesced float4 walk.
__global__ __launch_bounds__(256) void k_focal(const float4* __restrict__ cls4,
                                               float* __restrict__ cls_partial) {
    __shared__ float tab[TBL_N + 2];
    const int tid = threadIdx.x;
    for (int k = tid; k <= TBL_N; k += 256) {
        float x = (float)k * TBL_STEP - TBL_LO;
        float E = __expf(x);
        float den = 1.0f + E;
        float s = __builtin_amdgcn_rcpf(den);
        float p = E * s;
        float L = __logf(den);
        tab[k] = 0.75f * p * p * L;
    }
    __syncthreads();
    float acc = 0.0f;
    int i = blockIdx.x * 256 + tid;
    {
        unsigned int f = (unsigned int)i * 4u;
        unsigned int d = f / 21u;
        int r = (int)(f - d * 21u);
        const int stride = NB * 256;
        for (; i < TOTAL4; i += stride) {
            float4 x4 = cls4[i];
            float xs[4] = {x4.x, x4.y, x4.z, x4.w};
#pragma unroll
            for (int j = 0; j < 4; ++j) {
                int rr = r + j;                                   // in [0,23]; bg iff 0 or 21
                float u = fmaf(xs[j], TBL_SCALE, TBL_LO * TBL_SCALE);
                u = fminf(fmaxf(u, 0.0f), (float)TBL_N - 0.5f);
                int ii = (int)u;
                float fr = u - (float)ii;
                float v0 = tab[ii];
                float v1 = tab[ii + 1];
                float val = fmaf(fr, v1 - v0, v0);
                acc += (rr == 0 || rr == 21) ? 0.0f : val;
            }
            r += 8; if (r >= 21) r -= 21;                         // (stride*4) mod 21 == 8
        }
    }
#pragma unroll
    for (int s = 32; s >= 1; s >>= 1) acc += __shfl_xor(acc, s);
    __shared__ float s_acc[4];
    if ((tid & 63) == 0) s_acc[tid >> 6] = acc;
    __syncthreads();
    if (tid == 0) cls_partial[blockIdx.x] = s_acc[0] + s_acc[1] + s_acc[2] + s_acc[3];
}

// Kernel 2: single IoU pass. Per (chunk, batch): per-truth block argmax
// (-> bp_partial) AND per-anchor match + pre-override loc/corr/pos partials.
__global__ __launch_bounds__(256) void k_match(const float* __restrict__ cls,
                                               const float4* __restrict__ locp,
                                               const float4* __restrict__ anchors,
                                               const float4* __restrict__ truths,
                                               const int* __restrict__ labels,
                                               unsigned long long* __restrict__ bp_partial,
                                               float* __restrict__ loc_partial,
                                               float* __restrict__ corr_partial,
                                               unsigned int* __restrict__ pos_partial) {
    const int ch = blockIdx.x;
    const int b = blockIdx.y;
    const int tid = threadIdx.x;
    __shared__ float4 s_t[NOBJ];
    __shared__ float s_area[NOBJ];
    __shared__ int s_lab[NOBJ];
    __shared__ unsigned long long s_keys[8][256];
    if (tid < NOBJ) {
        float4 t = truths[b * NOBJ + tid];
        s_t[tid] = t;
        s_area[tid] = (t.z - t.x) * (t.w - t.y);
        s_lab[tid] = labels[b * NOBJ + tid];
    }
    __syncthreads();
    const int a0 = ch * CHUNK + tid;
    const bool has1 = tid < (CHUNK - 256);   // tid < 128
    const int a1 = a0 + 256;
    float4 an0 = anchors[a0];
    float4 an1 = anchors[has1 ? a1 : a0];
    float p0x0 = an0.x - an0.z * 0.5f, p0y0 = an0.y - an0.w * 0.5f;
    float p0x1 = an0.x + an0.z * 0.5f, p0y1 = an0.y + an0.w * 0.5f;
    float ap0 = (p0x1 - p0x0) * (p0y1 - p0y0);
    float p1x0 = an1.x - an1.z * 0.5f, p1y0 = an1.y - an1.w * 0.5f;
    float p1x1 = an1.x + an1.z * 0.5f, p1y1 = an1.y + an1.w * 0.5f;
    float ap1 = (p1x1 - p1x0) * (p1y1 - p1y0);
    float best0 = -1.0f, best1 = -1.0f;
    int idx0 = 0, idx1 = 0;
#pragma unroll
    for (int half = 0; half < 2; ++half) {
#pragma unroll
        for (int n = 0; n < 8; ++n) {
            const int nt = half * 8 + n;
            float4 t = s_t[nt];
            float at = s_area[nt];
            float iou0 = iou_pf(t.x, t.y, t.z, t.w, at, p0x0, p0y0, p0x1, p0y1, ap0);
            if (iou0 > best0) { best0 = iou0; idx0 = nt; }   // first-occurrence argmax
            unsigned long long key = pack_key(iou0, a0);
            if (has1) {
                float iou1 = iou_pf(t.x, t.y, t.z, t.w, at, p1x0, p1y0, p1x1, p1y1, ap1);
                if (iou1 > best1) { best1 = iou1; idx1 = nt; }
                unsigned long long k1 = pack_key(iou1, a1);
                key = (k1 > key) ? k1 : key;
            }
            s_keys[n][tid] = key;
        }
        __syncthreads();
        if (tid < 128) {
            const int g = tid >> 4, l = tid & 15;
            unsigned long long k = s_keys[g][l];
#pragma unroll
            for (int kk = 1; kk < 16; ++kk) {
                unsigned long long v = s_keys[g][l + 16 * kk];
                k = (v > k) ? v : k;
            }
#pragma unroll
            for (int s = 8; s >= 1; s >>= 1) {
                unsigned long long o = __shfl_xor(k, s);
                k = (o > k) ? o : k;
            }
            if (l == 0) bp_partial[(b * NOBJ + half * 8 + g) * NCH + ch] = k;
        }
        __syncthreads();
    }
    // per-anchor pre-override contributions
    float loc_l = 0.0f, corr = 0.0f;
    unsigned int pos = 0;
    if (!(best0 < 0.5f)) {
        pos++;
        int conf = s_lab[idx0];
        loc_l += loc_term(s_t[idx0], an0, locp[(size_t)b * A_COUNT + a0]);
        corr += corr_term(cls[((size_t)b * A_COUNT + a0) * C_COUNT + conf]);
    }
    if (has1 && !(best1 < 0.5f)) {
        pos++;
        int conf = s_lab[idx1];
        loc_l += loc_term(s_t[idx1], an1, locp[(size_t)b * A_COUNT + a1]);
        corr += corr_term(cls[((size_t)b * A_COUNT + a1) * C_COUNT + conf]);
    }
#pragma unroll
    for (int s = 32; s >= 1; s >>= 1) {
        loc_l += __shfl_xor(loc_l, s);
        corr += __shfl_xor(corr, s);
        pos += __shfl_xor(pos, s);
    }
    __shared__ float s_ll[4], s_cr[4];
    __shared__ unsigned int s_pp[4];
    if ((tid & 63) == 0) {
        s_ll[tid >> 6] = loc_l;
        s_cr[tid >> 6] = corr;
        s_pp[tid >> 6] = pos;
    }
    __syncthreads();
    if (tid == 0) {
        int bid = b * NCH + ch;
        loc_partial[bid] = s_ll[0] + s_ll[1] + s_ll[2] + s_ll[3];
        corr_partial[bid] = s_cr[0] + s_cr[1] + s_cr[2] + s_cr[3];
        pos_partial[bid] = s_pp[0] + s_pp[1] + s_pp[2] + s_pp[3];
    }
}

// Kernel 3 (1 block): reduce bp_partial -> forced-match winners -> exact delta
// corrections for the <=512 overridden anchors -> final double reduction.
__global__ __launch_bounds__(256) void k_fix_final(
        const float* __restrict__ cls,
        const float4* __restrict__ locp,
        const float4* __restrict__ anchors,
        const float4* __restrict__ truths,
        const int* __restrict__ labels,
        const unsigned long long* __restrict__ bp_partial,
        const float* __restrict__ loc_partial,
        const float* __restrict__ corr_partial,
        const unsigned int* __restrict__ pos_partial,
        const float* __restrict__ cls_partial,
        float* __restrict__ out) {
    const int tid = threadIdx.x;
    __shared__ int s_bp[B_COUNT * NOBJ];
    // Phase A: global best prior per (b,n); 16 lanes per row, 16 rows in flight
    {
        const int g16 = tid >> 4, l = tid & 15;
        for (int base = 0; base < B_COUNT * NOBJ; base += 16) {
            int row = base + g16;
            const unsigned long long* pp = &bp_partial[(size_t)row * NCH];
            unsigned long long k = pp[l];
            unsigned long long v;
            v = pp[l + 16]; k = (v > k) ? v : k;
            v = pp[l + 32]; k = (v > k) ? v : k;
            v = pp[l + 48]; k = (v > k) ? v : k;
#pragma unroll
            for (int s = 8; s >= 1; s >>= 1) {
                unsigned long long o = __shfl_xor(k, s);
                k = (o > k) ? o : k;
            }
            if (l == 0) {
                unsigned int ia = 0xFFFFFFFFu - (unsigned int)(k & 0xFFFFFFFFull);
                s_bp[row] = (ia >= A_COUNT) ? -1 : (int)ia;
            }
        }
    }
    __syncthreads();
    // Phase B/C: winner per forced anchor (last n wins), exact deltas
    float d_loc = 0.0f, d_corr = 0.0f;
    int d_pos = 0;
    for (int p = tid; p < B_COUNT * NOBJ; p += 256) {
        int b = p >> 4, n = p & 15;
        int q = s_bp[p];
        bool winner = (q >= 0);
        for (int n2 = n + 1; n2 < NOBJ; ++n2)
            if (s_bp[(b << 4) | n2] == q) winner = false;
        if (!winner) continue;
        float4 an = anchors[q];
        float px0 = an.x - an.z * 0.5f, py0 = an.y - an.w * 0.5f;
        float px1 = an.x + an.z * 0.5f, py1 = an.y + an.w * 0.5f;
        float ap = (px1 - px0) * (py1 - py0);
        float best = -1.0f;
        int idx = 0;
        for (int n2 = 0; n2 < NOBJ; ++n2) {          // identical order/math as k_match
            float4 t = truths[b * NOBJ + n2];
            float at = (t.z - t.x) * (t.w - t.y);
            float iou = iou_pf(t.x, t.y, t.z, t.w, at, px0, py0, px1, py1, ap);
            if (iou > best) { best = iou; idx = n2; }
        }
        float4 lp = locp[(size_t)b * A_COUNT + q];
        if (!(best < 0.5f)) {                        // remove original contribution
            d_pos -= 1;
            d_loc -= loc_term(truths[b * NOBJ + idx], an, lp);
            d_corr -= corr_term(cls[((size_t)b * A_COUNT + q) * C_COUNT + labels[b * NOBJ + idx]]);
        }
        d_pos += 1;                                  // add forced contribution
        d_loc += loc_term(truths[b * NOBJ + n], an, lp);
        d_corr += corr_term(cls[((size_t)b * A_COUNT + q) * C_COUNT + labels[b * NOBJ + n]]);
    }
    // Phase D: final reduction in double
    double loc = (double)d_loc, clsv = (double)d_corr;
    int pos = d_pos;
    for (int i = tid; i < NB; i += 256) {
        loc += (double)loc_partial[i];
        clsv += (double)corr_partial[i] + (double)cls_partial[i];
        pos += (int)pos_partial[i];
    }
#pragma unroll
    for (int s = 32; s >= 1; s >>= 1) {
        loc += __shfl_xor(loc, s);
        clsv += __shfl_xor(clsv, s);
        pos += __shfl_xor(pos, s);
    }
    __shared__ double s_l[4], s_c[4];
    __shared__ int s_p[4];
    if ((tid & 63) == 0) {
        s_l[tid >> 6] = loc;
        s_c[tid >> 6] = clsv;
        s_p[tid >> 6] = pos;
    }
    __syncthreads();
    if (tid == 0) {
        double L = s_l[0] + s_l[1] + s_l[2] + s_l[3];
        double Cv = s_c[0] + s_c[1] + s_c[2] + s_c[3];
        float nm = (float)(s_p[0] + s_p[1] + s_p[2] + s_p[3]);
        float cf = (float)Cv / nm;
        float lf = (float)L / nm;
        out[0] = cf;
        out[1] = lf;
        out[2] = cf + lf;
    }
}

extern "C" void kernel_launch(void* const* d_in, const int* in_sizes, int n_in,
                              void* d_out, int out_size, void* d_ws, size_t ws_size,
                              hipStream_t stream) {
    const float* cls = (const float*)d_in[0];
    const float4* locp = (const float4*)d_in[1];
    const float4* truths = (const float4*)d_in[2];
    const float4* anchors = (const float4*)d_in[3];
    const int* labels = (const int*)d_in[4];

    char* ws = (char*)d_ws;
    unsigned long long* bp_partial = (unsigned long long*)(ws + WS_BPP);
    float* loc_partial = (float*)(ws + WS_LOCP);
    float* corr_partial = (float*)(ws + WS_CORR);
    unsigned int* pos_partial = (unsigned int*)(ws + WS_POSP);
    float* cls_partial = (float*)(ws + WS_CLSP);

    k_focal<<<NB, 256, 0, stream>>>((const float4*)cls, cls_partial);
    k_match<<<dim3(NCH, B_COUNT), 256, 0, stream>>>(cls, locp, anchors, truths, labels,
                                                    bp_partial, loc_partial, corr_partial, pos_partial);
    k_fix_final<<<1, 256, 0, stream>>>(cls, locp, anchors, truths, labels, bp_partial,
                                       loc_partial, corr_partial, pos_partial, cls_partial,
                                       (float*)d_out);
}

// Round 7
// 42.993 us; speedup vs baseline: 1.4152x; 1.4152x over previous
//
#include <hip/hip_runtime.h>

#define A_COUNT 24576
#define B_COUNT 32
#define NOBJ 16
#define C_COUNT 21

#define NCH 64                      // anchor chunks per batch in k_main
#define CHUNK (A_COUNT / NCH)       // 384 anchors per block
#define NBLK (NCH * B_COUNT)        // 2048 blocks / partial slots
#define TOTAL4 (B_COUNT * A_COUNT * C_COUNT / 4)  // 4128768 float4

// ---- workspace layout (bytes); every slot fully rewritten every call ----
#define WS_BPP 0                    // u64 [B*NOBJ][NCH] = 256 KB
#define WS_LOCP 262144              // f32 [NBLK]
#define WS_CLSP 270336              // f32 [NBLK]
#define WS_POSP 278528              // u32 [NBLK]
#define WS_DLOC 286720              // f32 [B_COUNT]
#define WS_DCLS 286848              // f32 [B_COUNT]
#define WS_DPOS 286976              // i32 [B_COUNT]

__device__ __forceinline__ unsigned long long pack_key(float iou, int a) {
    unsigned int ib = __float_as_uint(iou);  // iou >= 0 so uint order == float order
    return ((unsigned long long)ib << 32) | (unsigned long long)(0xFFFFFFFFu - (unsigned int)a);
}

__device__ __forceinline__ float iou_pf(float tx0, float ty0, float tx1, float ty1, float at,
                                        float x0, float y0, float x1, float y1, float ap) {
    float lx = fmaxf(tx0, x0), ly = fmaxf(ty0, y0);
    float rx = fminf(tx1, x1), ry = fminf(ty1, y1);
    float w = fmaxf(rx - lx, 0.0f), h = fmaxf(ry - ly, 0.0f);
    float inter = w * h;
    return inter / (at + ap - inter);
}

__device__ __forceinline__ float sl1(float d) {
    float ad = fabsf(d);
    return (ad < 1.0f) ? 0.5f * d * d : ad - 0.5f;
}

__device__ __forceinline__ float loc_term(float4 t, float4 an, float4 lp) {
    float gx = ((t.x + t.z) * 0.5f - an.x) / (0.1f * an.z);
    float gy = ((t.y + t.w) * 0.5f - an.y) / (0.1f * an.w);
    float gw = __logf((t.z - t.x) / an.z) * 5.0f;
    float gh = __logf((t.w - t.y) / an.w) * 5.0f;
    return sl1(lp.x - gx) + sl1(lp.y - gy) + sl1(lp.z - gw) + sl1(lp.w - gh);
}

// exact focal correction at the matched class column:
// + 0.25*(1-p)^2*(-ln p)  - 0.75*p^2*ln(1+e^x)   (removes the t=0 main term)
__device__ __forceinline__ float corr_term(float x) {
    float E = __expf(x);
    float den = 1.0f + E;
    float s = __builtin_amdgcn_rcpf(den);   // 1-p
    float p = E * s;
    float L = __logf(den);                  // ln(1+e^x); -ln p = L - x
    return 0.25f * s * s * (L - x) - 0.75f * p * p * L;
}

// Kernel 1: single IoU pass (per-truth argmax -> bp_partial; per-anchor match ->
// pre-override loc/corr/pos) + grid-stride focal main term over all logits.
__global__ __launch_bounds__(256, 2) void k_main(const float* __restrict__ cls,
                                                 const float4* __restrict__ locp,
                                                 const float4* __restrict__ anchors,
                                                 const float4* __restrict__ truths,
                                                 const int* __restrict__ labels,
                                                 unsigned long long* __restrict__ bp_partial,
                                                 float* __restrict__ loc_partial,
                                                 float* __restrict__ cls_partial,
                                                 unsigned int* __restrict__ pos_partial) {
    const int ch = blockIdx.x;
    const int b = blockIdx.y;
    const int tid = threadIdx.x;
    __shared__ float4 s_t[NOBJ];
    __shared__ float s_area[NOBJ];
    __shared__ int s_lab[NOBJ];
    __shared__ unsigned long long s_keys[8][256];
    if (tid < NOBJ) {
        float4 t = truths[b * NOBJ + tid];
        s_t[tid] = t;
        s_area[tid] = (t.z - t.x) * (t.w - t.y);
        s_lab[tid] = labels[b * NOBJ + tid];
    }
    __syncthreads();
    const int a0 = ch * CHUNK + tid;
    const bool has1 = tid < (CHUNK - 256);   // tid < 128
    const int a1 = a0 + 256;
    float4 an0 = anchors[a0];
    float4 an1 = anchors[has1 ? a1 : a0];
    float p0x0 = an0.x - an0.z * 0.5f, p0y0 = an0.y - an0.w * 0.5f;
    float p0x1 = an0.x + an0.z * 0.5f, p0y1 = an0.y + an0.w * 0.5f;
    float ap0 = (p0x1 - p0x0) * (p0y1 - p0y0);
    float p1x0 = an1.x - an1.z * 0.5f, p1y0 = an1.y - an1.w * 0.5f;
    float p1x1 = an1.x + an1.z * 0.5f, p1y1 = an1.y + an1.w * 0.5f;
    float ap1 = (p1x1 - p1x0) * (p1y1 - p1y0);
    float best0 = -1.0f, best1 = -1.0f;
    int idx0 = 0, idx1 = 0;
#pragma unroll
    for (int half = 0; half < 2; ++half) {
#pragma unroll
        for (int n = 0; n < 8; ++n) {
            const int nt = half * 8 + n;
            float4 t = s_t[nt];
            float at = s_area[nt];
            float iou0 = iou_pf(t.x, t.y, t.z, t.w, at, p0x0, p0y0, p0x1, p0y1, ap0);
            if (iou0 > best0) { best0 = iou0; idx0 = nt; }   // first-occurrence argmax
            unsigned long long key = pack_key(iou0, a0);
            if (has1) {
                float iou1 = iou_pf(t.x, t.y, t.z, t.w, at, p1x0, p1y0, p1x1, p1y1, ap1);
                if (iou1 > best1) { best1 = iou1; idx1 = nt; }
                unsigned long long k1 = pack_key(iou1, a1);
                key = (k1 > key) ? k1 : key;
            }
            s_keys[n][tid] = key;
        }
        __syncthreads();
        if (tid < 128) {
            const int g = tid >> 4, l = tid & 15;
            unsigned long long k = s_keys[g][l];
#pragma unroll
            for (int kk = 1; kk < 16; ++kk) {
                unsigned long long v = s_keys[g][l + 16 * kk];
                k = (v > k) ? v : k;
            }
#pragma unroll
            for (int s = 8; s >= 1; s >>= 1) {
                unsigned long long o = __shfl_xor(k, s);
                k = (o > k) ? o : k;
            }
            if (l == 0) bp_partial[(b * NOBJ + half * 8 + g) * NCH + ch] = k;
        }
        __syncthreads();
    }
    // per-anchor pre-override contributions
    float loc_l = 0.0f, cls_acc = 0.0f;
    unsigned int pos = 0;
    if (!(best0 < 0.5f)) {
        pos++;
        loc_l += loc_term(s_t[idx0], an0, locp[(size_t)b * A_COUNT + a0]);
        cls_acc += corr_term(cls[((size_t)b * A_COUNT + a0) * C_COUNT + s_lab[idx0]]);
    }
    if (has1 && !(best1 < 0.5f)) {
        pos++;
        loc_l += loc_term(s_t[idx1], an1, locp[(size_t)b * A_COUNT + a1]);
        cls_acc += corr_term(cls[((size_t)b * A_COUNT + a1) * C_COUNT + s_lab[idx1]]);
    }

    // focal main term (t=0 form) for ALL non-background logits, coalesced stream
    const int bid = b * NCH + ch;
    {
        const float4* cls4 = (const float4*)cls;
        int i = bid * 256 + tid;
        unsigned int f = (unsigned int)i * 4u;
        unsigned int dq = f / 21u;
        int r = (int)(f - dq * 21u);
        const int stride = NBLK * 256;
        for (; i < TOTAL4; i += stride) {
            float4 x4 = cls4[i];
            float xs[4] = {x4.x, x4.y, x4.z, x4.w};
#pragma unroll
            for (int j = 0; j < 4; ++j) {
                int rr = r + j;                         // in [0,23]; bg iff 0 or 21
                float x = xs[j];
                float E = __expf(x);
                float den = 1.0f + E;
                float s = __builtin_amdgcn_rcpf(den);
                float p = E * s;
                float L = __logf(den);
                float v = p * p * L;
                float m = (rr == 0 || rr == 21) ? 0.0f : 0.75f;
                cls_acc = fmaf(v, m, cls_acc);
            }
            r += 8; if (r >= 21) r -= 21;               // (stride*4) mod 21 == 8
        }
    }

#pragma unroll
    for (int s = 32; s >= 1; s >>= 1) {
        loc_l += __shfl_xor(loc_l, s);
        cls_acc += __shfl_xor(cls_acc, s);
        pos += __shfl_xor(pos, s);
    }
    __shared__ float s_ll[4], s_cl[4];
    __shared__ unsigned int s_pp[4];
    if ((tid & 63) == 0) {
        s_ll[tid >> 6] = loc_l;
        s_cl[tid >> 6] = cls_acc;
        s_pp[tid >> 6] = pos;
    }
    __syncthreads();
    if (tid == 0) {
        loc_partial[bid] = s_ll[0] + s_ll[1] + s_ll[2] + s_ll[3];
        cls_partial[bid] = s_cl[0] + s_cl[1] + s_cl[2] + s_cl[3];
        pos_partial[bid] = s_pp[0] + s_pp[1] + s_pp[2] + s_pp[3];
    }
}

// Kernel 2: one block per batch: reduce bp_partial rows, forced-match winners
// (last n wins), exact delta corrections via bitwise-identical recompute.
__global__ __launch_bounds__(256) void k_fix(const float* __restrict__ cls,
                                             const float4* __restrict__ locp,
                                             const float4* __restrict__ anchors,
                                             const float4* __restrict__ truths,
                                             const int* __restrict__ labels,
                                             const unsigned long long* __restrict__ bp_partial,
                                             float* __restrict__ dloc,
                                             float* __restrict__ dcls,
                                             int* __restrict__ dpos) {
    const int b = blockIdx.x;
    const int tid = threadIdx.x;
    __shared__ int s_bp[NOBJ];
    {   // 16 rows x 16 lanes: global best prior per (b,n)
        const int g = tid >> 4, l = tid & 15;
        const unsigned long long* pp = &bp_partial[(size_t)(b * NOBJ + g) * NCH];
        unsigned long long k = pp[l];
        unsigned long long v;
        v = pp[l + 16]; k = (v > k) ? v : k;
        v = pp[l + 32]; k = (v > k) ? v : k;
        v = pp[l + 48]; k = (v > k) ? v : k;
#pragma unroll
        for (int s = 8; s >= 1; s >>= 1) {
            unsigned long long o = __shfl_xor(k, s);
            k = (o > k) ? o : k;
        }
        if (l == 0) {
            unsigned int ia = 0xFFFFFFFFu - (unsigned int)(k & 0xFFFFFFFFull);
            s_bp[g] = (ia >= A_COUNT) ? -1 : (int)ia;
        }
    }
    __syncthreads();
    float d_loc = 0.0f, d_cls = 0.0f;
    int d_pos = 0;
    if (tid < NOBJ) {
        const int n = tid;
        const int q = s_bp[n];
        bool winner = (q >= 0);
        for (int n2 = n + 1; n2 < NOBJ; ++n2)
            if (s_bp[n2] == q) winner = false;           // later truth wins the anchor
        if (winner) {
            float4 an = anchors[q];
            float px0 = an.x - an.z * 0.5f, py0 = an.y - an.w * 0.5f;
            float px1 = an.x + an.z * 0.5f, py1 = an.y + an.w * 0.5f;
            float ap = (px1 - px0) * (py1 - py0);
            float best = -1.0f;
            int idx = 0;
            for (int n2 = 0; n2 < NOBJ; ++n2) {          // identical order/math as k_main
                float4 t = truths[b * NOBJ + n2];
                float at = (t.z - t.x) * (t.w - t.y);
                float iou = iou_pf(t.x, t.y, t.z, t.w, at, px0, py0, px1, py1, ap);
                if (iou > best) { best = iou; idx = n2; }
            }
            float4 lp = locp[(size_t)b * A_COUNT + q];
            if (!(best < 0.5f)) {                        // remove original contribution
                d_pos -= 1;
                d_loc -= loc_term(truths[b * NOBJ + idx], an, lp);
                d_cls -= corr_term(cls[((size_t)b * A_COUNT + q) * C_COUNT + labels[b * NOBJ + idx]]);
            }
            d_pos += 1;                                  // add forced contribution
            d_loc += loc_term(truths[b * NOBJ + n], an, lp);
            d_cls += corr_term(cls[((size_t)b * A_COUNT + q) * C_COUNT + labels[b * NOBJ + n]]);
        }
    }
    if (tid < 64) {                                      // lanes 16..63 carry zeros
#pragma unroll
        for (int s = 8; s >= 1; s >>= 1) {
            d_loc += __shfl_xor(d_loc, s);
            d_cls += __shfl_xor(d_cls, s);
            d_pos += __shfl_xor(d_pos, s);
        }
        if (tid == 0) {
            dloc[b] = d_loc;
            dcls[b] = d_cls;
            dpos[b] = d_pos;
        }
    }
}

// Kernel 3: deterministic final reduction in double.
__global__ __launch_bounds__(256) void k_final(const float* __restrict__ loc_partial,
                                               const float* __restrict__ cls_partial,
                                               const unsigned int* __restrict__ pos_partial,
                                               const float* __restrict__ dloc,
                                               const float* __restrict__ dcls,
                                               const int* __restrict__ dpos,
                                               float* __restrict__ out) {
    const int tid = threadIdx.x;
    double loc = 0.0, clsv = 0.0;
    int pos = 0;
    for (int i = tid; i < NBLK; i += 256) {
        loc += (double)loc_partial[i];
        clsv += (double)cls_partial[i];
        pos += (int)pos_partial[i];
    }
    if (tid < B_COUNT) {
        loc += (double)dloc[tid];
        clsv += (double)dcls[tid];
        pos += dpos[tid];
    }
#pragma unroll
    for (int s = 32; s >= 1; s >>= 1) {
        loc += __shfl_xor(loc, s);
        clsv += __shfl_xor(clsv, s);
        pos += __shfl_xor(pos, s);
    }
    __shared__ double s_l[4], s_c[4];
    __shared__ int s_p[4];
    if ((tid & 63) == 0) {
        s_l[tid >> 6] = loc;
        s_c[tid >> 6] = clsv;
        s_p[tid >> 6] = pos;
    }
    __syncthreads();
    if (tid == 0) {
        double L = s_l[0] + s_l[1] + s_l[2] + s_l[3];
        double Cv = s_c[0] + s_c[1] + s_c[2] + s_c[3];
        float nm = (float)(s_p[0] + s_p[1] + s_p[2] + s_p[3]);
        float cf = (float)Cv / nm;
        float lf = (float)L / nm;
        out[0] = cf;
        out[1] = lf;
        out[2] = cf + lf;
    }
}

extern "C" void kernel_launch(void* const* d_in, const int* in_sizes, int n_in,
                              void* d_out, int out_size, void* d_ws, size_t ws_size,
                              hipStream_t stream) {
    const float* cls = (const float*)d_in[0];
    const float4* locp = (const float4*)d_in[1];
    const float4* truths = (const float4*)d_in[2];
    const float4* anchors = (const float4*)d_in[3];
    const int* labels = (const int*)d_in[4];

    char* ws = (char*)d_ws;
    unsigned long long* bp_partial = (unsigned long long*)(ws + WS_BPP);
    float* loc_partial = (float*)(ws + WS_LOCP);
    float* cls_partial = (float*)(ws + WS_CLSP);
    unsigned int* pos_partial = (unsigned int*)(ws + WS_POSP);
    float* dloc = (float*)(ws + WS_DLOC);
    float* dcls = (float*)(ws + WS_DCLS);
    int* dpos = (int*)(ws + WS_DPOS);

    k_main<<<dim3(NCH, B_COUNT), 256, 0, stream>>>(cls, locp, anchors, truths, labels,
                                                   bp_partial, loc_partial, cls_partial, pos_partial);
    k_fix<<<B_COUNT, 256, 0, stream>>>(cls, locp, anchors, truths, labels, bp_partial,
                                       dloc, dcls, dpos);
    k_final<<<1, 256, 0, stream>>>(loc_partial, cls_partial, pos_partial, dloc, dcls, dpos,
                                   (float*)d_out);
}